// Round 6
// baseline (95.407 us; speedup 1.0000x reference)
//
#include <hip/hip_runtime.h>
#include <hip/hip_bf16.h>
#include <math.h>

#define D_   64
#define HW_  4096
#define N_   16384
#define M_   4096

// ws layout (floats)
#define AEN_OFF 0            // anl*||e_m||^2  [4096]
#define SUM_OFF 4096         // sums[4096]
#define EBF_OFF 8192         // e bf16 [4096][64] = 131072 floats
#define WS_FLOATS (EBF_OFF + 131072)

#define L2E 1.4426950408889634f

typedef __attribute__((ext_vector_type(8))) short short8;
typedef __attribute__((ext_vector_type(16))) float floatx16;

#if __has_builtin(__builtin_amdgcn_exp2f)
#define EXP2F(x) __builtin_amdgcn_exp2f(x)
#else
#define EXP2F(x) exp2f(x)
#endif

__device__ __forceinline__ unsigned int bf16_rne(float x) {
    unsigned int u = __float_as_uint(x);
    u += 0x7fffu + ((u >> 16) & 1u);
    return u >> 16;
}

// 16 blocks: e -> bf16 rows, aen = anl*||e||^2, zero sums
__global__ void prep_e(const float* __restrict__ e,
                       const float* __restrict__ lsp,
                       float* __restrict__ ws) {
    const float ls = lsp[0];
    const float alpha = -0.5f * __expf(-2.f * ls);
    const float anl = alpha * L2E;
    unsigned short* ebf = (unsigned short*)(ws + EBF_OFF);
    int m = blockIdx.x * 256 + threadIdx.x;
    const float4* ep = (const float4*)(e + (size_t)m * D_);
    float s = 0.f;
    unsigned int pk[32];
#pragma unroll
    for (int k = 0; k < 16; ++k) {
        float4 v = ep[k];
        s += v.x * v.x + v.y * v.y + v.z * v.z + v.w * v.w;
        pk[2 * k]     = bf16_rne(v.x) | (bf16_rne(v.y) << 16);
        pk[2 * k + 1] = bf16_rne(v.z) | (bf16_rne(v.w) << 16);
    }
    uint4* op = (uint4*)(ebf + (size_t)m * 64);
#pragma unroll
    for (int k = 0; k < 8; ++k)
        op[k] = make_uint4(pk[4 * k], pk[4 * k + 1], pk[4 * k + 2], pk[4 * k + 3]);
    ws[AEN_OFF + m] = anl * s;
    ws[SUM_OFF + m] = 0.f;
}

// 512 blocks x 256 thr: block owns 32 z-rows (LDS-resident, bf16 log2-prescaled),
// streams all 4096 e-codes in 64-col tiles; 4 waves each cover 16 staggered tiles.
__global__ __launch_bounds__(256, 3) void main_fast(
        const float* __restrict__ z, const float* __restrict__ lsp,
        float* __restrict__ ws) {
    __shared__ unsigned short zlds[32 * 64];   // 4 KB, XOR-swizzled [row][d]
    __shared__ float azn_lds[32];

    const unsigned short* ebf = (const unsigned short*)(ws + EBF_OFF);
    const float* aen = ws + AEN_OFF;
    float* sums = ws + SUM_OFF;

    const int t = threadIdx.x;
    const int lane = t & 63;
    const int w = t >> 6;
    const int rlo = lane & 31;
    const int kh = lane >> 5;
    const int bx = (int)blockIdx.x;

    const float ls = lsp[0];
    const float alpha = -0.5f * __expf(-2.f * ls);
    const float anl = alpha * L2E;         // azn scale (log2 domain)
    const float c2p = -2.f * alpha * L2E;  // z pre-scale (log2 domain)

    const int n0 = bx * 32;
    const int b = n0 >> 12, hw0 = n0 & 4095;

    // ---- transpose 32 z-rows into LDS (bf16, pre-scaled) + row norms ----
    {
        const int g = t & 7;        // hw chunk of 4
        const int db = t >> 3;      // d base 0..31
        float part[4] = {0.f, 0.f, 0.f, 0.f};
#pragma unroll
        for (int h = 0; h < 2; ++h) {
            int d = db + 32 * h;
            float4 v = *(const float4*)(z + ((size_t)(b * D_ + d)) * HW_ + hw0 + g * 4);
            float vv[4] = {v.x, v.y, v.z, v.w};
#pragma unroll
            for (int q = 0; q < 4; ++q) {
                int hw = g * 4 + q;
                int unit = hw * 8 + ((d >> 3) ^ (hw & 7));
                zlds[unit * 8 + (d & 7)] = (unsigned short)bf16_rne(vv[q] * c2p);
                part[q] = fmaf(vv[q], vv[q], part[q]);
            }
        }
#pragma unroll
        for (int q = 0; q < 4; ++q) {
            part[q] += __shfl_xor(part[q], 8);
            part[q] += __shfl_xor(part[q], 16);
            part[q] += __shfl_xor(part[q], 32);
        }
        if (t < 32) azn_lds[t] = 0.f;
        __syncthreads();
        if (lane < 8) {
#pragma unroll
            for (int q = 0; q < 4; ++q)
                atomicAdd(&azn_lds[lane * 4 + q], part[q]);
        }
        __syncthreads();
    }

    // ---- A fragments (shared 32 rows) + azn, register-resident ----
    short8 af[4];
#pragma unroll
    for (int ks = 0; ks < 4; ++ks) {
        int unit = rlo * 8 + ((ks * 2 + kh) ^ (rlo & 7));
        af[ks] = *(const short8*)&zlds[unit * 8];
    }
    float azn_r[16];
#pragma unroll
    for (int rg = 0; rg < 4; ++rg) {
        float4 vv = *(const float4*)&azn_lds[4 * kh + 8 * rg];
        azn_r[rg * 4 + 0] = vv.x * anl; azn_r[rg * 4 + 1] = vv.y * anl;
        azn_r[rg * 4 + 2] = vv.z * anl; azn_r[rg * 4 + 3] = vv.w * anl;
    }

    // ---- stream e: 16 staggered 64-col tiles per wave, double-buffered ----
    short8 bfc[2][4]; float aenc[2];
    {
        int mt = w + 4 * (bx & 15);
        int m0 = mt * 64;
#pragma unroll
        for (int ms = 0; ms < 2; ++ms) {
            int row = m0 + ms * 32 + rlo;
            aenc[ms] = aen[row];
#pragma unroll
            for (int ks = 0; ks < 4; ++ks)
                bfc[ms][ks] = *(const short8*)(ebf + (size_t)row * 64 + (ks * 2 + kh) * 8);
        }
    }

    for (int j = 0; j < 16; ++j) {
        short8 bfn[2][4]; float aenn[2];
        if (j < 15) {
            int mt = w + 4 * ((j + 1 + bx) & 15);
            int m0 = mt * 64;
#pragma unroll
            for (int ms = 0; ms < 2; ++ms) {
                int row = m0 + ms * 32 + rlo;
                aenn[ms] = aen[row];
#pragma unroll
                for (int ks = 0; ks < 4; ++ks)
                    bfn[ms][ks] = *(const short8*)(ebf + (size_t)row * 64 + (ks * 2 + kh) * 8);
            }
        }

        floatx16 acc[2];
#pragma unroll
        for (int ms = 0; ms < 2; ++ms)
#pragma unroll
            for (int r = 0; r < 16; ++r)
                acc[ms][r] = azn_r[r] + aenc[ms];

#pragma unroll
        for (int ks = 0; ks < 4; ++ks)
#pragma unroll
            for (int ms = 0; ms < 2; ++ms)
                acc[ms] = __builtin_amdgcn_mfma_f32_32x32x16_bf16(
                    af[ks], bfc[ms][ks], acc[ms], 0, 0, 0);

        float s0 = 0.f, s1 = 0.f;
#pragma unroll
        for (int r = 0; r < 16; ++r) s0 += EXP2F(acc[0][r]);
#pragma unroll
        for (int r = 0; r < 16; ++r) s1 += EXP2F(acc[1][r]);
        s0 += __shfl_down(s0, 32);
        s1 += __shfl_down(s1, 32);

        int mt = w + 4 * ((j + bx) & 15);
        int m0 = mt * 64;
        if (lane < 32) {
            atomicAdd(&sums[m0 + lane], s0);
            atomicAdd(&sums[m0 + 32 + lane], s1);
        }

#pragma unroll
        for (int ms = 0; ms < 2; ++ms) {
            aenc[ms] = aenn[ms];
#pragma unroll
            for (int ks = 0; ks < 4; ++ks) bfc[ms][ks] = bfn[ms][ks];
        }
    }
}

__global__ void finalize_fast(const float* __restrict__ ws,
                              const float* __restrict__ lsp,
                              float* __restrict__ out) {
    __shared__ double red[256];
    const float* sums = ws + SUM_OFF;
    int t = threadIdx.x;
    double local = 0.0;
#pragma unroll
    for (int j = 0; j < 16; ++j) {
        float s = sums[t + 256 * j];
        local += (double)logf(s);
    }
    red[t] = local;
    __syncthreads();
    for (int off = 128; off > 0; off >>= 1) {
        if (t < off) red[t] += red[t + off];
        __syncthreads();
    }
    if (t == 0) {
        double ls = (double)lsp[0];
        double loss = -(red[0] / (double)M_)
                      + 0.5 * (double)D_ * (2.0 * ls - 1.0)
                      + log((double)N_);
        out[0] = (float)loss;
    }
}

extern "C" void kernel_launch(void* const* d_in, const int* in_sizes, int n_in,
                              void* d_out, int out_size, void* d_ws, size_t ws_size,
                              hipStream_t stream) {
    const float* z   = (const float*)d_in[0];
    const float* e   = (const float*)d_in[1];
    const float* lsp = (const float*)d_in[2];
    float* ws  = (float*)d_ws;
    float* out = (float*)d_out;

    hipLaunchKernelGGL(prep_e, dim3(16), dim3(256), 0, stream, e, lsp, ws);
    hipLaunchKernelGGL(main_fast, dim3(N_ / 32), dim3(256), 0, stream, z, lsp, ws);
    hipLaunchKernelGGL(finalize_fast, dim3(1), dim3(256), 0, stream, ws, lsp, out);
}

// Round 7
// 82.463 us; speedup vs baseline: 1.1570x; 1.1570x over previous
//
#include <hip/hip_runtime.h>
#include <hip/hip_bf16.h>
#include <math.h>

#define D_   64
#define HW_  4096
#define N_   16384
#define M_   4096

// ---- geometry ----
#define BM 128                 // codes per block (e-rows register-resident)
#define NSPLIT 16              // n-splits across grid
#define NCHUNK (N_ / NSPLIT)   // 1024 rows per block
#define NTILES (NCHUNK / 128)  // 8 tiles of 128 rows (4 waves x 32)

// ---- ws layout (floats) ----
#define AZN_OFF 0                      // azn'[16384]  (log2-domain row norms)
#define AEN_OFF 16384                  // aen'[4096]   (log2-domain col norms)
#define SUM_OFF 20480                  // sums[4096]
#define ZTB_OFF 24576                  // zT bf16 [16384][64] = 524288 floats
#define EBF_OFF (24576 + 524288)       // e  bf16 [4096][64]  = 131072 floats
#define WS_FLOATS (EBF_OFF + 131072)

#define L2E 1.4426950408889634f
#define LN2 0.6931471805599453

typedef __attribute__((ext_vector_type(8))) short short8;
typedef __attribute__((ext_vector_type(16))) float floatx16;

#if __has_builtin(__builtin_amdgcn_exp2f)
#define EXP2F(x) __builtin_amdgcn_exp2f(x)
#else
#define EXP2F(x) exp2f(x)
#endif

__device__ __forceinline__ unsigned int bf16_rne(float x) {
    unsigned int u = __float_as_uint(x);
    u += 0x7fffu + ((u >> 16) & 1u);
    return u >> 16;
}

// blocks 0..255: z transpose+scale+norm ; blocks 256..271: e convert+norm+zero sums
__global__ void prep_kernel(const float* __restrict__ z,
                            const float* __restrict__ e,
                            const float* __restrict__ lsp,
                            float* __restrict__ ws) {
    const float ls = lsp[0];
    const float alpha = -0.5f * __expf(-2.f * ls);   // -1/(2 e^{2ls})
    const float anl = alpha * L2E;                   // norm scale (log2 domain)
    const float c2p = -2.f * alpha * L2E;            // z pre-scale (log2 domain)
    unsigned short* zTb = (unsigned short*)(ws + ZTB_OFF);
    unsigned short* ebf = (unsigned short*)(ws + EBF_OFF);
    const int blk = blockIdx.x, t = threadIdx.x;

    if (blk < 256) {
        __shared__ float lt[64 * 65];
        const int b = blk >> 6, hw0 = (blk & 63) * 64;
        const int n0 = b * HW_ + hw0;
        const float* zb = z + ((size_t)b * D_) * HW_ + hw0;
#pragma unroll
        for (int i = 0; i < 4; ++i) {
            int idx = t + 256 * i;
            int d = idx >> 4, c = (idx & 15) * 4;
            float4 v = *(const float4*)(zb + (size_t)d * HW_ + c);
            float* p = &lt[d * 65 + c];
            p[0] = v.x; p[1] = v.y; p[2] = v.z; p[3] = v.w;
        }
        __syncthreads();
#pragma unroll
        for (int j = 0; j < 2; ++j) {
            int idx = t + 256 * j;
            int nl = idx >> 3, g = idx & 7;
            float v[8]; float s = 0.f;
#pragma unroll
            for (int jj = 0; jj < 8; ++jj) {
                v[jj] = lt[(8 * g + jj) * 65 + nl];
                s = fmaf(v[jj], v[jj], s);
            }
            s += __shfl_xor(s, 1);
            s += __shfl_xor(s, 2);
            s += __shfl_xor(s, 4);
            uint4 pk;
            pk.x = bf16_rne(v[0] * c2p) | (bf16_rne(v[1] * c2p) << 16);
            pk.y = bf16_rne(v[2] * c2p) | (bf16_rne(v[3] * c2p) << 16);
            pk.z = bf16_rne(v[4] * c2p) | (bf16_rne(v[5] * c2p) << 16);
            pk.w = bf16_rne(v[6] * c2p) | (bf16_rne(v[7] * c2p) << 16);
            *(uint4*)(zTb + (size_t)(n0 + nl) * 64 + 8 * g) = pk;
            if (g == 0) ws[AZN_OFF + n0 + nl] = anl * s;
        }
    } else {
        int m = (blk - 256) * 256 + t;
        const float4* ep = (const float4*)(e + (size_t)m * D_);
        float s = 0.f;
        unsigned int pk[32];
#pragma unroll
        for (int k = 0; k < 16; ++k) {
            float4 v = ep[k];
            s += v.x * v.x + v.y * v.y + v.z * v.z + v.w * v.w;
            pk[2 * k]     = bf16_rne(v.x) | (bf16_rne(v.y) << 16);
            pk[2 * k + 1] = bf16_rne(v.z) | (bf16_rne(v.w) << 16);
        }
        uint4* op = (uint4*)(ebf + (size_t)m * 64);
#pragma unroll
        for (int k = 0; k < 8; ++k)
            op[k] = make_uint4(pk[4 * k], pk[4 * k + 1], pk[4 * k + 2], pk[4 * k + 3]);
        ws[AEN_OFF + m] = anl * s;
        ws[SUM_OFF + m] = 0.f;
    }
}

// grid (32,16), 256 thr: B (e, 128 rows) register-resident; 8 A-tiles of 128 rows
// with register double-buffer prefetch; aen factored OUT (added in finalize).
__global__ __launch_bounds__(256, 2) void main_fast(float* __restrict__ ws) {
    __shared__ float lds_red[BM];
    const unsigned short* zTb = (const unsigned short*)(ws + ZTB_OFF);
    const unsigned short* ebf = (const unsigned short*)(ws + EBF_OFF);
    const float* azn = ws + AZN_OFF;
    float* sums = ws + SUM_OFF;

    const int m0 = blockIdx.x * BM;
    const int ns = blockIdx.y;
    const int t = threadIdx.x;
    const int lane = t & 63;
    const int w = t >> 6;
    const int rlo = lane & 31;
    const int kh = lane >> 5;

    // B fragments: 128 e-rows register-resident (64 VGPR)
    short8 bf[4][4];
#pragma unroll
    for (int mt = 0; mt < 4; ++mt) {
        int row = m0 + mt * 32 + rlo;
#pragma unroll
        for (int ks = 0; ks < 4; ++ks)
            bf[mt][ks] = *(const short8*)(ebf + (size_t)row * 64 + (ks * 2 + kh) * 8);
    }

    float sum[4] = {0.f, 0.f, 0.f, 0.f};
    const int nbase = ns * NCHUNK + w * 32;

    // prefetch tile 0
    short8 afc[4];
    float4 aznc[4];
    {
#pragma unroll
        for (int ks = 0; ks < 4; ++ks)
            afc[ks] = *(const short8*)(zTb + (size_t)(nbase + rlo) * 64 + (ks * 2 + kh) * 8);
        const int r0 = nbase + 4 * kh;
#pragma unroll
        for (int rg = 0; rg < 4; ++rg) aznc[rg] = *(const float4*)(azn + r0 + 8 * rg);
    }

#pragma unroll
    for (int tile = 0; tile < NTILES; ++tile) {
        short8 afn[4];
        float4 aznn[4];
        if (tile + 1 < NTILES) {
            const int nr = nbase + (tile + 1) * 128;
#pragma unroll
            for (int ks = 0; ks < 4; ++ks)
                afn[ks] = *(const short8*)(zTb + (size_t)(nr + rlo) * 64 + (ks * 2 + kh) * 8);
            const int r0 = nr + 4 * kh;
#pragma unroll
            for (int rg = 0; rg < 4; ++rg) aznn[rg] = *(const float4*)(azn + r0 + 8 * rg);
        }

        float azn_r[16];
#pragma unroll
        for (int rg = 0; rg < 4; ++rg) {
            azn_r[rg * 4 + 0] = aznc[rg].x; azn_r[rg * 4 + 1] = aznc[rg].y;
            azn_r[rg * 4 + 2] = aznc[rg].z; azn_r[rg * 4 + 3] = aznc[rg].w;
        }

        floatx16 acc[4];
#pragma unroll
        for (int mt = 0; mt < 4; ++mt)
#pragma unroll
            for (int r = 0; r < 16; ++r)
                acc[mt][r] = azn_r[r];           // aen factored out

#pragma unroll
        for (int ks = 0; ks < 4; ++ks)
#pragma unroll
            for (int mt = 0; mt < 4; ++mt)
                acc[mt] = __builtin_amdgcn_mfma_f32_32x32x16_bf16(
                    afc[ks], bf[mt][ks], acc[mt], 0, 0, 0);

#pragma unroll
        for (int mt = 0; mt < 4; ++mt) {
            float s = 0.f;
#pragma unroll
            for (int r = 0; r < 16; ++r) s += EXP2F(acc[mt][r]);
            sum[mt] += s;
        }

#pragma unroll
        for (int ks = 0; ks < 4; ++ks) afc[ks] = afn[ks];
#pragma unroll
        for (int rg = 0; rg < 4; ++rg) aznc[rg] = aznn[rg];
    }

#pragma unroll
    for (int mt = 0; mt < 4; ++mt) sum[mt] += __shfl_down(sum[mt], 32);

    if (t < BM) lds_red[t] = 0.f;
    __syncthreads();
    if (lane < 32) {
#pragma unroll
        for (int mt = 0; mt < 4; ++mt) atomicAdd(&lds_red[mt * 32 + rlo], sum[mt]);
    }
    __syncthreads();
    if (t < BM) atomicAdd(&sums[m0 + t], lds_red[t]);
}

__global__ void finalize_fast(const float* __restrict__ ws,
                              const float* __restrict__ lsp,
                              float* __restrict__ out) {
    __shared__ double red[256];
    const float* sums = ws + SUM_OFF;
    const float* aen = ws + AEN_OFF;
    int t = threadIdx.x;
    double local = 0.0;
#pragma unroll
    for (int j = 0; j < 16; ++j) {
        int m = t + 256 * j;
        // lse_m = ln2 * (aen'_m + log2(S_m))
        local += (double)(aen[m] + log2f(sums[m]));
    }
    red[t] = local;
    __syncthreads();
    for (int off = 128; off > 0; off >>= 1) {
        if (t < off) red[t] += red[t + off];
        __syncthreads();
    }
    if (t == 0) {
        double ls = (double)lsp[0];
        double loss = -(LN2 * red[0] / (double)M_)
                      + 0.5 * (double)D_ * (2.0 * ls - 1.0)
                      + log((double)N_);
        out[0] = (float)loss;
    }
}

extern "C" void kernel_launch(void* const* d_in, const int* in_sizes, int n_in,
                              void* d_out, int out_size, void* d_ws, size_t ws_size,
                              hipStream_t stream) {
    const float* z   = (const float*)d_in[0];
    const float* e   = (const float*)d_in[1];
    const float* lsp = (const float*)d_in[2];
    float* ws  = (float*)d_ws;
    float* out = (float*)d_out;

    hipLaunchKernelGGL(prep_kernel, dim3(272), dim3(256), 0, stream, z, e, lsp, ws);
    hipLaunchKernelGGL(main_fast, dim3(M_ / BM, NSPLIT), dim3(256), 0, stream, ws);
    hipLaunchKernelGGL(finalize_fast, dim3(1), dim3(256), 0, stream, ws, lsp, out);
}